// Round 20
// baseline (105.176 us; speedup 1.0000x reference)
//
#include <hip/hip_runtime.h>
#include <hip/hip_fp16.h>

#define NELEM 8388608    // 8*256*64*64
#define M_GAP 6e-4f      // validated rounds 6/8/9/13 (fp16 1-plane, x1024 codebook)
#define SCORE_SCALE (-1.0f / 512.0f)

typedef _Float16 f16x8 __attribute__((ext_vector_type(8)));
typedef short s16x8 __attribute__((ext_vector_type(8)));
typedef float f32x4 __attribute__((ext_vector_type(4)));

__device__ __forceinline__ unsigned short bf16r(float f) {
  unsigned u = __float_as_uint(f);
  return (unsigned short)((u + 0x7fffu + ((u >> 16) & 1u)) >> 16);
}
__device__ __forceinline__ float bf16f(unsigned short h) {
  return __uint_as_float(((unsigned)h) << 16);
}

// numpy pairwise sum of squares (n=256): two 128-blocks of 8 accumulators.
__device__ __forceinline__ float pw128_sq(const float* p, int s) {
  float r[8];
#pragma unroll
  for (int j = 0; j < 8; ++j) { float v = p[j * s]; r[j] = __fmul_rn(v, v); }
#pragma unroll
  for (int i = 8; i < 128; i += 8) {
#pragma unroll
    for (int j = 0; j < 8; ++j) {
      float v = p[(i + j) * s];
      r[j] = __fadd_rn(r[j], __fmul_rn(v, v));
    }
  }
  return __fadd_rn(__fadd_rn(__fadd_rn(r[0], r[1]), __fadd_rn(r[2], r[3])),
                   __fadd_rn(__fadd_rn(r[4], r[5]), __fadd_rn(r[6], r[7])));
}
__device__ __forceinline__ float np_sumsq256(const float* p, int s) {
  return __fadd_rn(pw128_sq(p, s), pw128_sq(p + 128 * s, s));
}

// ---- prep (LDS transpose): 64 blocks, block b owns codes [b*16, b*16+16) ----
__global__ __launch_bounds__(256)
void vq_prep(const float* __restrict__ cb, unsigned short* __restrict__ cbimg,
             float* __restrict__ cbT, float* __restrict__ Bsg,
             unsigned* __restrict__ cnt, float* __restrict__ loss) {
  __shared__ float rows[16][260];
  const int t = threadIdx.x;
  const int b = blockIdx.x;            // tile T = b
  if (b == 0 && t == 0) { cnt[0] = 0u; *loss = 0.0f; }
#pragma unroll
  for (int i = 0; i < 4; ++i) {
    int idx = t + i * 256;             // r = idx>>6, c4 = idx&63
    int r = idx >> 6, c4 = idx & 63;
    float4 v = reinterpret_cast<const float4*>(cb + (size_t)(b * 16 + r) * 256)[c4];
    rows[r][c4 * 4 + 0] = v.x;
    rows[r][c4 * 4 + 1] = v.y;
    rows[r][c4 * 4 + 2] = v.z;
    rows[r][c4 * 4 + 3] = v.w;
  }
  __syncthreads();
  if (t < 16) Bsg[b * 16 + t] = np_sumsq256(&rows[t][0], 1);
  // cbimg frag layout: short idx T*4096 + kk*512 + (lk*16+jj)*8 + m
#pragma unroll
  for (int uu = 0; uu < 2; ++uu) {
    int u = t * 2 + uu;
    int kk = u >> 6, rem = u & 63;
    int lk = rem >> 4, jj = rem & 15;
    int c0 = kk * 32 + lk * 8;
    s16x8 hv;
#pragma unroll
    for (int m = 0; m < 8; ++m)
      hv[m] = (short)__half_as_ushort(__float2half(rows[jj][c0 + m] * 1024.0f));
    *reinterpret_cast<s16x8*>(cbimg + (size_t)b * 4096 + u * 8) = hv;
  }
  // cbT stripe: thread t = column c, 16 consecutive floats (line-efficient)
  {
    float* dst = cbT + (size_t)t * 1024 + b * 16;
#pragma unroll
    for (int jj = 0; jj < 16; ++jj) dst[jj] = rows[jj][t];
  }
}

// one 16-code tile: 8 kk MFMA x 2 row-subtiles + top-2 update; next tile's
// B-frag load issued right after ba[kk] is consumed. Macro so no register
// array is address-taken (rule #20).
#define VQ_STEP_PF(IT2, DO_PF)                                                 \
  {                                                                            \
    f32x4 acc[2];                                                              \
    acc[0] = (f32x4){0.f, 0.f, 0.f, 0.f};                                      \
    acc[1] = (f32x4){0.f, 0.f, 0.f, 0.f};                                      \
    _Pragma("unroll")                                                          \
    for (int kk = 0; kk < 8; ++kk) {                                           \
      f16x8 bcur = ba[kk];                                                     \
      if (DO_PF)                                                               \
        ba[kk] = cimg2[(size_t)(wv * 16 + (IT2) + 1) * 512 + kk * 64 + lane];  \
      _Pragma("unroll")                                                        \
      for (int rs = 0; rs < 2; ++rs)                                           \
        acc[rs] = __builtin_amdgcn_mfma_f32_16x16x32_f16(ah[rs][kk], bcur,     \
                                                         acc[rs], 0, 0, 0);    \
    }                                                                          \
    int j = wv * 256 + (IT2) * 16 + l15;                                       \
    float Bj = BsL[j];                                                         \
    _Pragma("unroll")                                                          \
    for (int rs = 0; rs < 2; ++rs) {                                           \
      _Pragma("unroll")                                                        \
      for (int r = 0; r < 4; ++r) {                                            \
        float s = fmaf(SCORE_SCALE, acc[rs][r], Bj);                           \
        bool lt = s < b1v[rs][r];                                              \
        float other = lt ? b1v[rs][r] : s;                                     \
        b2v[rs][r] = fminf(b2v[rs][r], other);                                 \
        b1v[rs][r] = fminf(b1v[rs][r], s);                                     \
        b1i[rs][r] = lt ? j : b1i[rs][r];                                      \
      }                                                                        \
    }                                                                          \
  }

// ---- fast: 1024 blocks x 32 rows, 4 waves code-partitioned, B global->reg ----
__global__ __launch_bounds__(256, 1)
void vq_fast(const float* __restrict__ z, const float* __restrict__ cb,
             const unsigned short* __restrict__ cbimg,
             const float* __restrict__ Bsg,
             float* __restrict__ zq, float* __restrict__ loss,
             float* __restrict__ idxo,
             unsigned* __restrict__ list, unsigned* __restrict__ cnt,
             float* __restrict__ zdump) {
  __shared__ __align__(16) unsigned char buf[33792]; // zt[256][33] f32 / epilogue ldsF 32KB
  __shared__ float BsL[1024];
  __shared__ float part[32][33];
  __shared__ float rowA[32];
  __shared__ int bestj[32];
  __shared__ float bestd[32];
  __shared__ unsigned char flg[32];
  __shared__ float wred[4];
  __shared__ float cv1[4 * 32], cv2[4 * 32];
  __shared__ int ci1[4 * 32];

  const int t = threadIdx.x;
  const int bid = blockIdx.x;          // rows n0 = bid*32
  const int lane = t & 63;
  const int wv = t >> 6;               // wave 0..3: codes wv*256..+255
  const int l15 = lane & 15;
  const int lk = lane >> 4;            // 0..3
  const int bh = bid >> 1, half = bid & 1;

  const f16x8* cimg2 = reinterpret_cast<const f16x8*>(cbimg);  // 16B units
  float* zt = reinterpret_cast<float*>(buf);   // [256 c][33] f32 during A-stage
  const float4* z4 = reinterpret_cast<const float4*>(
      z + (size_t)(bh >> 6) * 1048576 + (size_t)(bh & 63) * 64 + half * 32);

  // issue tile-0 loads of this wave's quarter early (latency under A-stage)
  f16x8 ba[8];
#pragma unroll
  for (int kk = 0; kk < 8; ++kk)
    ba[kk] = cimg2[(size_t)(wv * 16) * 512 + kk * 64 + lane];

  for (int i = t; i < 1024; i += 256) BsL[i] = Bsg[i];

  // ---- A staging: 32 rows in one pass ----
  {
    float sq[4] = {0.f, 0.f, 0.f, 0.f};
#pragma unroll
    for (int i = 0; i < 8; ++i) {
      int idx = t + i * 256;           // c = idx>>3, w4p = idx&7
      int c = idx >> 3, w4p = idx & 7;
      float4 v = z4[(size_t)c * 1024 + w4p];
      zt[c * 33 + w4p * 4 + 0] = v.x;
      zt[c * 33 + w4p * 4 + 1] = v.y;
      zt[c * 33 + w4p * 4 + 2] = v.z;
      zt[c * 33 + w4p * 4 + 3] = v.w;
      sq[0] += v.x * v.x; sq[1] += v.y * v.y;
      sq[2] += v.z * v.z; sq[3] += v.w * v.w;
    }
#pragma unroll
    for (int q = 0; q < 4; ++q) part[t >> 3][(t & 7) * 4 + q] = sq[q];
  }
  __syncthreads();
  if (t < 32) {
    float s = 0.f;
#pragma unroll
    for (int g = 0; g < 32; ++g) s += part[g][t];
    rowA[t] = s;
  }

  // a-frags: all 32 rows (2 subtiles), fp16 RNE
  f16x8 ah[2][8];
#pragma unroll
  for (int rs = 0; rs < 2; ++rs)
#pragma unroll
    for (int kk = 0; kk < 8; ++kk)
#pragma unroll
      for (int m = 0; m < 8; ++m)
        ah[rs][kk][m] = (_Float16)zt[(kk * 32 + lk * 8 + m) * 33 + rs * 16 + l15];
  __syncthreads();

  float b1v[2][4], b2v[2][4];
  int b1i[2][4];
#pragma unroll
  for (int rs = 0; rs < 2; ++rs)
#pragma unroll
    for (int r = 0; r < 4; ++r) { b1v[rs][r] = 3.4e38f; b2v[rs][r] = 3.4e38f; b1i[rs][r] = 0; }

  // barrier-free main loop over this wave's 16 private tiles
  for (int it = 0; it < 15; ++it) {
    VQ_STEP_PF(it, true);
  }
  VQ_STEP_PF(15, false);

  // ---- merge top-2 across the 16 lanes sharing rows (within wave) ----
#pragma unroll
  for (int mk = 1; mk < 16; mk <<= 1) {
#pragma unroll
    for (int rs = 0; rs < 2; ++rs)
#pragma unroll
      for (int r = 0; r < 4; ++r) {
        float ov1 = __shfl_xor(b1v[rs][r], mk, 64);
        float ov2 = __shfl_xor(b2v[rs][r], mk, 64);
        int oi1 = __shfl_xor(b1i[rs][r], mk, 64);
        bool lt = ov1 < b1v[rs][r];
        float hi = lt ? b1v[rs][r] : ov1;
        b2v[rs][r] = fminf(fminf(b2v[rs][r], ov2), hi);
        b1v[rs][r] = fminf(b1v[rs][r], ov1);
        b1i[rs][r] = lt ? oi1 : b1i[rs][r];
      }
  }
  if (l15 == 0) {
#pragma unroll
    for (int rs = 0; rs < 2; ++rs)
#pragma unroll
      for (int r = 0; r < 4; ++r) {
        int rr = rs * 16 + lk * 4 + r;     // D row = (lane>>4)*4 + reg
        cv1[wv * 32 + rr] = b1v[rs][r];
        cv2[wv * 32 + rr] = b2v[rs][r];
        ci1[wv * 32 + rr] = b1i[rs][r];
      }
  }
  __syncthreads();

  // ---- cross-wave merge (wave order = ascending code ranges) ----
  if (t < 32) {
    float v1 = cv1[t], v2 = cv2[t];
    int i1 = ci1[t];
#pragma unroll
    for (int w = 1; w < 4; ++w) {
      float u1 = cv1[w * 32 + t], u2 = cv2[w * 32 + t];
      int ui = ci1[w * 32 + t];
      if (u1 < v1) { v2 = fminf(v1, u2); v1 = u1; i1 = ui; }
      else v2 = fminf(v2, u1);
    }
    bestj[t] = i1;
    bestd[t] = v1;
    flg[t] = (v2 - v1 <= M_GAP) ? 1 : 0;
    int n = bid * 32 + t;
    idxo[n] = (float)i1;               // provisional for flagged rows
    if (flg[t]) { unsigned pos = atomicAdd(cnt, 1u); list[pos] = (unsigned)n; }
  }
  __syncthreads();

  // ---- zdump ONLY for flagged rows (zt still live in buf) ----
  for (int rr = 0; rr < 32; ++rr) {
    if (flg[rr])
      zdump[((size_t)bid * 32 + rr) * 256 + t] = zt[t * 33 + rr];
  }

  // loss over ALL rows (flagged rows' provisional s_best within tolerance)
  {
    float lv = (t < 32) ? (rowA[t] + bestd[t]) : 0.f;
#pragma unroll
    for (int off = 32; off > 0; off >>= 1) lv += __shfl_down(lv, off, 64);
    if (lane == 0) wred[wv] = lv;
  }
  __syncthreads();
  if (t == 0)
    atomicAdd(loss, (wred[0] + wred[1] + wred[2] + wred[3]) * (1.25f / (float)NELEM));
  __syncthreads();   // zdump reads of zt done before buf is reused below

  // ---- zq gather: cb rows -> LDS transpose -> coalesced write (32 rows) ----
  f32x4* ldsF4 = reinterpret_cast<f32x4*>(buf);
  const float* ldsF = reinterpret_cast<const float*>(buf);
  const float4* cb4 = reinterpret_cast<const float4*>(cb);
  float* zqb = zq + (size_t)(bh >> 6) * 1048576 + (size_t)(bh & 63) * 64 + half * 32;
#pragma unroll
  for (int i = 0; i < 8; ++i) {
    int item = t + i * 256;            // rr = item>>6 in [0,32), cc = item&63
    int rr = item >> 6, cc = item & 63;
    float4 v = cb4[(size_t)bestj[rr] * 64 + cc];
    ldsF4[rr * 64 + (cc ^ ((rr >> 2) & 7))] = (f32x4){v.x, v.y, v.z, v.w};
  }
  __syncthreads();
#pragma unroll
  for (int i = 0; i < 8; ++i) {
    int item = t + i * 256;            // w4p = item&7, c = item>>3
    int w4p = item & 7, c = item >> 3;
    float ov[4];
#pragma unroll
    for (int q = 0; q < 4; ++q) {
      int rr = w4p * 4 + q;
      ov[q] = ldsF[(rr * 64 + ((c >> 2) ^ ((rr >> 2) & 7))) * 4 + (c & 3)];
    }
    *reinterpret_cast<float4*>(zqb + (size_t)c * 4096 + w4p * 4) =
        make_float4(ov[0], ov[1], ov[2], ov[3]);
  }
}

// ---- exact rescore: 8 rows/block, 8-deep pipelined cbT stream, 1-barrier
//      argmin. Same np-chain numerics and first-index tie-breaks as before. ----
__global__ __launch_bounds__(256)
void vq_exact_fast(const float* __restrict__ zdump, const float* __restrict__ cbT,
                   const float* __restrict__ Bsg, const unsigned* __restrict__ list,
                   const unsigned* __restrict__ cnt, float* __restrict__ idxo) {
  __shared__ float zr[8][260];
  __shared__ float Anp[8];
  __shared__ float rvs[8][256];
  __shared__ int ris[8][256];
  const int t = threadIdx.x;
  const unsigned K = *cnt;
  const float4* cbT4 = reinterpret_cast<const float4*>(cbT);
  const float4* zd4 = reinterpret_cast<const float4*>(zdump);

  for (unsigned g = blockIdx.x; g * 8 < K; g += gridDim.x) {
    int nrows = (int)min(8u, K - g * 8);
    __syncthreads();                     // guard shared reuse across iterations
#pragma unroll
    for (int i = 0; i < 2; ++i) {
      int idx = t + i * 256;             // r = idx>>6, c4 = idx&63
      int r = idx >> 6, c4 = idx & 63;
      if (r < nrows) {
        float4 v = zd4[(size_t)list[g * 8 + r] * 64 + c4];
        zr[r][c4 * 4 + 0] = v.x; zr[r][c4 * 4 + 1] = v.y;
        zr[r][c4 * 4 + 2] = v.z; zr[r][c4 * 4 + 3] = v.w;
      }
    }
    __syncthreads();
    if (t < nrows) Anp[t] = np_sumsq256(&zr[t][0], 1);
    __syncthreads();

    // C chains: 8-deep software-pipelined cbT stream (c ascending per chain)
    float acc[8][4];
#pragma unroll
    for (int r = 0; r < 8; ++r)
#pragma unroll
      for (int q = 0; q < 4; ++q) acc[r][q] = 0.f;
    float4 pre0, pre1, pre2, pre3, pre4, pre5, pre6, pre7;
    pre0 = cbT4[0 * 256 + t]; pre1 = cbT4[1 * 256 + t];
    pre2 = cbT4[2 * 256 + t]; pre3 = cbT4[3 * 256 + t];
    pre4 = cbT4[4 * 256 + t]; pre5 = cbT4[5 * 256 + t];
    pre6 = cbT4[6 * 256 + t]; pre7 = cbT4[7 * 256 + t];
    for (int cg = 0; cg < 256; cg += 8) {
      float4 cur0 = pre0, cur1 = pre1, cur2 = pre2, cur3 = pre3;
      float4 cur4 = pre4, cur5 = pre5, cur6 = pre6, cur7 = pre7;
      if (cg + 8 < 256) {
        pre0 = cbT4[(cg + 8) * 256 + t];  pre1 = cbT4[(cg + 9) * 256 + t];
        pre2 = cbT4[(cg + 10) * 256 + t]; pre3 = cbT4[(cg + 11) * 256 + t];
        pre4 = cbT4[(cg + 12) * 256 + t]; pre5 = cbT4[(cg + 13) * 256 + t];
        pre6 = cbT4[(cg + 14) * 256 + t]; pre7 = cbT4[(cg + 15) * 256 + t];
      }
#define EX_FMA(CUR, CI)                                                        \
      {                                                                        \
        float4 bv = CUR;                                                       \
        _Pragma("unroll")                                                      \
        for (int r = 0; r < 8; ++r) {                                          \
          float zc = zr[r][cg + (CI)];                                         \
          acc[r][0] = fmaf(zc, bv.x, acc[r][0]);                               \
          acc[r][1] = fmaf(zc, bv.y, acc[r][1]);                               \
          acc[r][2] = fmaf(zc, bv.z, acc[r][2]);                               \
          acc[r][3] = fmaf(zc, bv.w, acc[r][3]);                               \
        }                                                                      \
      }
      EX_FMA(cur0, 0) EX_FMA(cur1, 1) EX_FMA(cur2, 2) EX_FMA(cur3, 3)
      EX_FMA(cur4, 4) EX_FMA(cur5, 5) EX_FMA(cur6, 6) EX_FMA(cur7, 7)
#undef EX_FMA
    }

    // per-thread best over codes {4t..4t+3} per row -> LDS (first-index kept)
#pragma unroll
    for (int r = 0; r < 8; ++r) {
      float A = Anp[r];
      float bvv = 3.4e38f;
      int bii = 0;
#pragma unroll
      for (int q = 0; q < 4; ++q) {
        int j = t * 4 + q;
        float dd = __fsub_rn(__fadd_rn(A, Bsg[j]), __fmul_rn(2.0f, acc[r][q]));
        if (dd < bvv) { bvv = dd; bii = j; }
      }
      rvs[r][t] = bvv; ris[r][t] = bii;
    }
    __syncthreads();

    // single-barrier final reduce: 32 threads per row, strided scan + shfl
    {
      int r = t >> 5, s = t & 31;
      if (r < nrows) {
        float v0 = rvs[r][s]; int i0 = ris[r][s];
#pragma unroll
        for (int k = 1; k < 8; ++k) {
          float v = rvs[r][s + 32 * k]; int ii = ris[r][s + 32 * k];
          if (v < v0 || (v == v0 && ii < i0)) { v0 = v; i0 = ii; }
        }
#pragma unroll
        for (int mk = 1; mk < 32; mk <<= 1) {
          float v = __shfl_xor(v0, mk, 32); int ii = __shfl_xor(i0, mk, 32);
          if (v < v0 || (v == v0 && ii < i0)) { v0 = v; i0 = ii; }
        }
        if (s == 0) idxo[list[g * 8 + r]] = (float)i0;
      }
    }
  }
}

// ---- fallback (round-2 validated all-exact kernel) ----
__global__ __launch_bounds__(256)
void vq_ref(const float* __restrict__ z, const float* __restrict__ cb,
            float* __restrict__ zq, float* __restrict__ loss,
            float* __restrict__ idxo) {
  __shared__ __align__(16) float zt[256 * 64];
  __shared__ __align__(16) float cbt[256 * 64];
  __shared__ float As[64];
  __shared__ float Bs[64];
  __shared__ int bestj[64];
  __shared__ float cand_v[16 * 64];
  __shared__ int cand_i[16 * 64];
  __shared__ double wred[4];
  const int t = threadIdx.x;
  const int wg = t & 15, jg = t >> 4;
  const int bid = blockIdx.x;
  const int b = bid >> 6, h = bid & 63;
  const int n0 = bid * 64;
  const float4* z4 = reinterpret_cast<const float4*>(z + (size_t)b * 256 * 4096 + (size_t)h * 64);
  float4* zt4 = reinterpret_cast<float4*>(zt);
#pragma unroll
  for (int i = 0; i < 16; ++i) {
    int idx4 = t + i * 256;
    zt4[idx4] = z4[(size_t)(idx4 >> 4) * 1024 + (idx4 & 15)];
  }
  __syncthreads();
  if (t < 64) As[t] = np_sumsq256(zt + t, 64);
  float bv[4]; int bi[4];
#pragma unroll
  for (int a = 0; a < 4; ++a) { bv[a] = 3.4e38f; bi[a] = 0; }
  for (int p = 0; p < 16; ++p) {
    __syncthreads();
    const float4* cb4 = reinterpret_cast<const float4*>(cb) + (size_t)p * 64 * 64;
#pragma unroll
    for (int i = 0; i < 16; ++i) {
      int idx4 = t + i * 256;
      int jj = idx4 >> 6, c4 = idx4 & 63;
      float4 v = cb4[idx4];
      cbt[(c4 * 4 + 0) * 64 + jj] = v.x;
      cbt[(c4 * 4 + 1) * 64 + jj] = v.y;
      cbt[(c4 * 4 + 2) * 64 + jj] = v.z;
      cbt[(c4 * 4 + 3) * 64 + jj] = v.w;
    }
    __syncthreads();
    if (t < 64) Bs[t] = np_sumsq256(cbt + t, 64);
    float acc[4][4];
#pragma unroll
    for (int a = 0; a < 4; ++a)
#pragma unroll
      for (int u = 0; u < 4; ++u) acc[a][u] = 0.0f;
    const float4* ztp = reinterpret_cast<const float4*>(zt) + wg;
    const float4* cbp = reinterpret_cast<const float4*>(cbt) + jg;
#pragma unroll 4
    for (int c = 0; c < 256; ++c) {
      float4 zv = ztp[c * 16];
      float4 cv = cbp[c * 16];
      float za[4] = {zv.x, zv.y, zv.z, zv.w};
      float ca[4] = {cv.x, cv.y, cv.z, cv.w};
#pragma unroll
      for (int a = 0; a < 4; ++a)
#pragma unroll
        for (int u = 0; u < 4; ++u) acc[a][u] = fmaf(za[a], ca[u], acc[a][u]);
    }
    __syncthreads();
#pragma unroll
    for (int u = 0; u < 4; ++u) {
      int j = p * 64 + jg * 4 + u;
      float Bju = Bs[jg * 4 + u];
#pragma unroll
      for (int a = 0; a < 4; ++a) {
        float AB = __fadd_rn(As[wg * 4 + a], Bju);
        float dd = __fsub_rn(AB, __fmul_rn(2.0f, acc[a][u]));
        if (dd < bv[a]) { bv[a] = dd; bi[a] = j; }
      }
    }
  }
  __syncthreads();
#pragma unroll
  for (int a = 0; a < 4; ++a) {
    int w = wg * 4 + a;
    cand_v[jg * 64 + w] = bv[a];
    cand_i[jg * 64 + w] = bi[a];
  }
  __syncthreads();
  if (t < 64) {
    float v0 = cand_v[t]; int i0 = cand_i[t];
    for (int g = 1; g < 16; ++g) {
      float v = cand_v[g * 64 + t]; int ii = cand_i[g * 64 + t];
      if (v < v0 || (v == v0 && ii < i0)) { v0 = v; i0 = ii; }
    }
    bestj[t] = i0;
    idxo[n0 + t] = (float)i0;
  }
  __syncthreads();
  double lsum = 0.0;
  float* zqbase = zq + (size_t)b * 256 * 4096 + (size_t)h * 64;
  for (int i = 0; i < 64; ++i) {
    int idx = t + i * 256;
    int c = idx >> 6, w = idx & 63;
    float zvv = zt[c * 64 + w];
    float cvv = cb[(size_t)bestj[w] * 256 + c];
    zqbase[(size_t)c * 4096 + w] = cvv;
    double d = (double)cvv - (double)zvv;
    lsum += d * d;
  }
#pragma unroll
  for (int off = 32; off > 0; off >>= 1) lsum += __shfl_down(lsum, off, 64);
  if ((t & 63) == 0) wred[t >> 6] = lsum;
  __syncthreads();
  if (t == 0) {
    double tot = wred[0] + wred[1] + wred[2] + wred[3];
    atomicAdd(loss, (float)(tot * (1.25 / (double)NELEM)));
  }
}

extern "C" void kernel_launch(void* const* d_in, const int* in_sizes, int n_in,
                              void* d_out, int out_size, void* d_ws, size_t ws_size,
                              hipStream_t stream) {
  (void)in_sizes; (void)n_in; (void)out_size;
  const float* z = (const float*)d_in[0];
  const float* cb = (const float*)d_in[1];
  float* out = (float*)d_out;
  float* zq = out;
  float* loss = out + NELEM;
  float* idxo = out + NELEM + 1;
  if (ws_size < 35651584) {  // need zdump: else validated all-exact path
    hipMemsetAsync(loss, 0, sizeof(float), stream);
    vq_ref<<<512, 256, 0, stream>>>(z, cb, zq, loss, idxo);
    return;
  }
  unsigned char* ws = (unsigned char*)d_ws;
  unsigned* cnt = (unsigned*)ws;                             // 4 B
  float* Bsg = (float*)(ws + 1024);                          // 4 KB
  unsigned* list = (unsigned*)(ws + 8192);                   // 128 KB
  float* cbT = (float*)(ws + 139264);                        // 1 MB
  unsigned short* cbimg = (unsigned short*)(ws + 1187840);   // 512 KB fp16 frag-layout
  float* zdump = (float*)(ws + 2097152);                     // 32 MB (flagged rows only)
  vq_prep<<<64, 256, 0, stream>>>(cb, cbimg, cbT, Bsg, cnt, loss);
  vq_fast<<<1024, 256, 0, stream>>>(z, cb, cbimg, Bsg, zq, loss, idxo, list, cnt, zdump);
  vq_exact_fast<<<512, 256, 0, stream>>>(zdump, cbT, Bsg, list, cnt, idxo);
}

// Round 21
// 104.736 us; speedup vs baseline: 1.0042x; 1.0042x over previous
//
#include <hip/hip_runtime.h>
#include <hip/hip_fp16.h>

#define NELEM 8388608    // 8*256*64*64
#define M_GAP 6e-4f      // validated rounds 6/8/9/13 (fp16 1-plane, x1024 codebook)
#define SCORE_SCALE (-1.0f / 512.0f)

typedef _Float16 f16x8 __attribute__((ext_vector_type(8)));
typedef short s16x8 __attribute__((ext_vector_type(8)));
typedef float f32x4 __attribute__((ext_vector_type(4)));

__device__ __forceinline__ unsigned short bf16r(float f) {
  unsigned u = __float_as_uint(f);
  return (unsigned short)((u + 0x7fffu + ((u >> 16) & 1u)) >> 16);
}
__device__ __forceinline__ float bf16f(unsigned short h) {
  return __uint_as_float(((unsigned)h) << 16);
}

// numpy pairwise sum of squares (n=256): two 128-blocks of 8 accumulators.
__device__ __forceinline__ float pw128_sq(const float* p, int s) {
  float r[8];
#pragma unroll
  for (int j = 0; j < 8; ++j) { float v = p[j * s]; r[j] = __fmul_rn(v, v); }
#pragma unroll
  for (int i = 8; i < 128; i += 8) {
#pragma unroll
    for (int j = 0; j < 8; ++j) {
      float v = p[(i + j) * s];
      r[j] = __fadd_rn(r[j], __fmul_rn(v, v));
    }
  }
  return __fadd_rn(__fadd_rn(__fadd_rn(r[0], r[1]), __fadd_rn(r[2], r[3])),
                   __fadd_rn(__fadd_rn(r[4], r[5]), __fadd_rn(r[6], r[7])));
}
__device__ __forceinline__ float np_sumsq256(const float* p, int s) {
  return __fadd_rn(pw128_sq(p, s), pw128_sq(p + 128 * s, s));
}

// ---- prep (LDS transpose): 64 blocks, block b owns codes [b*16, b*16+16) ----
__global__ __launch_bounds__(256)
void vq_prep(const float* __restrict__ cb, unsigned short* __restrict__ cbimg,
             float* __restrict__ cbT, float* __restrict__ Bsg,
             unsigned* __restrict__ cnt, float* __restrict__ loss) {
  __shared__ float rows[16][260];
  const int t = threadIdx.x;
  const int b = blockIdx.x;            // tile T = b
  if (b == 0 && t == 0) { cnt[0] = 0u; *loss = 0.0f; }
#pragma unroll
  for (int i = 0; i < 4; ++i) {
    int idx = t + i * 256;             // r = idx>>6, c4 = idx&63
    int r = idx >> 6, c4 = idx & 63;
    float4 v = reinterpret_cast<const float4*>(cb + (size_t)(b * 16 + r) * 256)[c4];
    rows[r][c4 * 4 + 0] = v.x;
    rows[r][c4 * 4 + 1] = v.y;
    rows[r][c4 * 4 + 2] = v.z;
    rows[r][c4 * 4 + 3] = v.w;
  }
  __syncthreads();
  if (t < 16) Bsg[b * 16 + t] = np_sumsq256(&rows[t][0], 1);
  // cbimg frag layout: short idx T*4096 + kk*512 + (lk*16+jj)*8 + m
#pragma unroll
  for (int uu = 0; uu < 2; ++uu) {
    int u = t * 2 + uu;
    int kk = u >> 6, rem = u & 63;
    int lk = rem >> 4, jj = rem & 15;
    int c0 = kk * 32 + lk * 8;
    s16x8 hv;
#pragma unroll
    for (int m = 0; m < 8; ++m)
      hv[m] = (short)__half_as_ushort(__float2half(rows[jj][c0 + m] * 1024.0f));
    *reinterpret_cast<s16x8*>(cbimg + (size_t)b * 4096 + u * 8) = hv;
  }
  // cbT stripe: thread t = column c, 16 consecutive floats (line-efficient)
  {
    float* dst = cbT + (size_t)t * 1024 + b * 16;
#pragma unroll
    for (int jj = 0; jj < 16; ++jj) dst[jj] = rows[jj][t];
  }
}

// one 16-code tile: 8 kk MFMA x 2 row-subtiles + top-2 update; next tile's
// B-frag load issued right after ba[kk] is consumed. Macro so no register
// array is address-taken (rule #20).
#define VQ_STEP_PF(IT2, DO_PF)                                                 \
  {                                                                            \
    f32x4 acc[2];                                                              \
    acc[0] = (f32x4){0.f, 0.f, 0.f, 0.f};                                      \
    acc[1] = (f32x4){0.f, 0.f, 0.f, 0.f};                                      \
    _Pragma("unroll")                                                          \
    for (int kk = 0; kk < 8; ++kk) {                                           \
      f16x8 bcur = ba[kk];                                                     \
      if (DO_PF)                                                               \
        ba[kk] = cimg2[(size_t)(wv * 16 + (IT2) + 1) * 512 + kk * 64 + lane];  \
      _Pragma("unroll")                                                        \
      for (int rs = 0; rs < 2; ++rs)                                           \
        acc[rs] = __builtin_amdgcn_mfma_f32_16x16x32_f16(ah[rs][kk], bcur,     \
                                                         acc[rs], 0, 0, 0);    \
    }                                                                          \
    int j = wv * 256 + (IT2) * 16 + l15;                                       \
    float Bj = BsL[j];                                                         \
    _Pragma("unroll")                                                          \
    for (int rs = 0; rs < 2; ++rs) {                                           \
      _Pragma("unroll")                                                        \
      for (int r = 0; r < 4; ++r) {                                            \
        float s = fmaf(SCORE_SCALE, acc[rs][r], Bj);                           \
        bool lt = s < b1v[rs][r];                                              \
        float other = lt ? b1v[rs][r] : s;                                     \
        b2v[rs][r] = fminf(b2v[rs][r], other);                                 \
        b1v[rs][r] = fminf(b1v[rs][r], s);                                     \
        b1i[rs][r] = lt ? j : b1i[rs][r];                                      \
      }                                                                        \
    }                                                                          \
  }

// ---- fast: 1024 blocks x 32 rows, 4 waves code-partitioned, B global->reg ----
__global__ __launch_bounds__(256, 1)
void vq_fast(const float* __restrict__ z, const float* __restrict__ cb,
             const unsigned short* __restrict__ cbimg,
             const float* __restrict__ Bsg,
             float* __restrict__ zq, float* __restrict__ loss,
             float* __restrict__ idxo,
             unsigned* __restrict__ list, unsigned* __restrict__ cnt,
             float* __restrict__ zdump) {
  __shared__ __align__(16) unsigned char buf[33792]; // zt[256][33] f32 / epilogue ldsF 32KB
  __shared__ float BsL[1024];
  __shared__ float part[32][33];
  __shared__ float rowA[32];
  __shared__ int bestj[32];
  __shared__ float bestd[32];
  __shared__ unsigned char flg[32];
  __shared__ float wred[4];
  __shared__ float cv1[4 * 32], cv2[4 * 32];
  __shared__ int ci1[4 * 32];

  const int t = threadIdx.x;
  const int bid = blockIdx.x;          // rows n0 = bid*32
  const int lane = t & 63;
  const int wv = t >> 6;               // wave 0..3: codes wv*256..+255
  const int l15 = lane & 15;
  const int lk = lane >> 4;            // 0..3
  const int bh = bid >> 1, half = bid & 1;

  const f16x8* cimg2 = reinterpret_cast<const f16x8*>(cbimg);  // 16B units
  float* zt = reinterpret_cast<float*>(buf);   // [256 c][33] f32 during A-stage
  const float4* z4 = reinterpret_cast<const float4*>(
      z + (size_t)(bh >> 6) * 1048576 + (size_t)(bh & 63) * 64 + half * 32);

  // issue tile-0 loads of this wave's quarter early (latency under A-stage)
  f16x8 ba[8];
#pragma unroll
  for (int kk = 0; kk < 8; ++kk)
    ba[kk] = cimg2[(size_t)(wv * 16) * 512 + kk * 64 + lane];

  for (int i = t; i < 1024; i += 256) BsL[i] = Bsg[i];

  // ---- A staging: 32 rows in one pass ----
  {
    float sq[4] = {0.f, 0.f, 0.f, 0.f};
#pragma unroll
    for (int i = 0; i < 8; ++i) {
      int idx = t + i * 256;           // c = idx>>3, w4p = idx&7
      int c = idx >> 3, w4p = idx & 7;
      float4 v = z4[(size_t)c * 1024 + w4p];
      zt[c * 33 + w4p * 4 + 0] = v.x;
      zt[c * 33 + w4p * 4 + 1] = v.y;
      zt[c * 33 + w4p * 4 + 2] = v.z;
      zt[c * 33 + w4p * 4 + 3] = v.w;
      sq[0] += v.x * v.x; sq[1] += v.y * v.y;
      sq[2] += v.z * v.z; sq[3] += v.w * v.w;
    }
#pragma unroll
    for (int q = 0; q < 4; ++q) part[t >> 3][(t & 7) * 4 + q] = sq[q];
  }
  __syncthreads();
  if (t < 32) {
    float s = 0.f;
#pragma unroll
    for (int g = 0; g < 32; ++g) s += part[g][t];
    rowA[t] = s;
  }

  // a-frags: all 32 rows (2 subtiles), fp16 RNE
  f16x8 ah[2][8];
#pragma unroll
  for (int rs = 0; rs < 2; ++rs)
#pragma unroll
    for (int kk = 0; kk < 8; ++kk)
#pragma unroll
      for (int m = 0; m < 8; ++m)
        ah[rs][kk][m] = (_Float16)zt[(kk * 32 + lk * 8 + m) * 33 + rs * 16 + l15];
  __syncthreads();

  float b1v[2][4], b2v[2][4];
  int b1i[2][4];
#pragma unroll
  for (int rs = 0; rs < 2; ++rs)
#pragma unroll
    for (int r = 0; r < 4; ++r) { b1v[rs][r] = 3.4e38f; b2v[rs][r] = 3.4e38f; b1i[rs][r] = 0; }

  // barrier-free main loop over this wave's 16 private tiles
  for (int it = 0; it < 15; ++it) {
    VQ_STEP_PF(it, true);
  }
  VQ_STEP_PF(15, false);

  // ---- merge top-2 across the 16 lanes sharing rows (within wave) ----
#pragma unroll
  for (int mk = 1; mk < 16; mk <<= 1) {
#pragma unroll
    for (int rs = 0; rs < 2; ++rs)
#pragma unroll
      for (int r = 0; r < 4; ++r) {
        float ov1 = __shfl_xor(b1v[rs][r], mk, 64);
        float ov2 = __shfl_xor(b2v[rs][r], mk, 64);
        int oi1 = __shfl_xor(b1i[rs][r], mk, 64);
        bool lt = ov1 < b1v[rs][r];
        float hi = lt ? b1v[rs][r] : ov1;
        b2v[rs][r] = fminf(fminf(b2v[rs][r], ov2), hi);
        b1v[rs][r] = fminf(b1v[rs][r], ov1);
        b1i[rs][r] = lt ? oi1 : b1i[rs][r];
      }
  }
  if (l15 == 0) {
#pragma unroll
    for (int rs = 0; rs < 2; ++rs)
#pragma unroll
      for (int r = 0; r < 4; ++r) {
        int rr = rs * 16 + lk * 4 + r;     // D row = (lane>>4)*4 + reg
        cv1[wv * 32 + rr] = b1v[rs][r];
        cv2[wv * 32 + rr] = b2v[rs][r];
        ci1[wv * 32 + rr] = b1i[rs][r];
      }
  }
  __syncthreads();

  // ---- cross-wave merge (wave order = ascending code ranges) ----
  if (t < 32) {
    float v1 = cv1[t], v2 = cv2[t];
    int i1 = ci1[t];
#pragma unroll
    for (int w = 1; w < 4; ++w) {
      float u1 = cv1[w * 32 + t], u2 = cv2[w * 32 + t];
      int ui = ci1[w * 32 + t];
      if (u1 < v1) { v2 = fminf(v1, u2); v1 = u1; i1 = ui; }
      else v2 = fminf(v2, u1);
    }
    bestj[t] = i1;
    bestd[t] = v1;
    flg[t] = (v2 - v1 <= M_GAP) ? 1 : 0;
    int n = bid * 32 + t;
    idxo[n] = (float)i1;               // provisional for flagged rows
    if (flg[t]) { unsigned pos = atomicAdd(cnt, 1u); list[pos] = (unsigned)n; }
  }
  __syncthreads();

  // ---- zdump ONLY for flagged rows (zt still live in buf) ----
  for (int rr = 0; rr < 32; ++rr) {
    if (flg[rr])
      zdump[((size_t)bid * 32 + rr) * 256 + t] = zt[t * 33 + rr];
  }

  // loss over ALL rows (flagged rows' provisional s_best within tolerance)
  {
    float lv = (t < 32) ? (rowA[t] + bestd[t]) : 0.f;
#pragma unroll
    for (int off = 32; off > 0; off >>= 1) lv += __shfl_down(lv, off, 64);
    if (lane == 0) wred[wv] = lv;
  }
  __syncthreads();
  if (t == 0)
    atomicAdd(loss, (wred[0] + wred[1] + wred[2] + wred[3]) * (1.25f / (float)NELEM));
  __syncthreads();   // zdump reads of zt done before buf is reused below

  // ---- zq gather: cb rows -> LDS transpose -> coalesced write (32 rows) ----
  f32x4* ldsF4 = reinterpret_cast<f32x4*>(buf);
  const float* ldsF = reinterpret_cast<const float*>(buf);
  const float4* cb4 = reinterpret_cast<const float4*>(cb);
  float* zqb = zq + (size_t)(bh >> 6) * 1048576 + (size_t)(bh & 63) * 64 + half * 32;
#pragma unroll
  for (int i = 0; i < 8; ++i) {
    int item = t + i * 256;            // rr = item>>6 in [0,32), cc = item&63
    int rr = item >> 6, cc = item & 63;
    float4 v = cb4[(size_t)bestj[rr] * 64 + cc];
    ldsF4[rr * 64 + (cc ^ ((rr >> 2) & 7))] = (f32x4){v.x, v.y, v.z, v.w};
  }
  __syncthreads();
#pragma unroll
  for (int i = 0; i < 8; ++i) {
    int item = t + i * 256;            // w4p = item&7, c = item>>3
    int w4p = item & 7, c = item >> 3;
    float ov[4];
#pragma unroll
    for (int q = 0; q < 4; ++q) {
      int rr = w4p * 4 + q;
      ov[q] = ldsF[(rr * 64 + ((c >> 2) ^ ((rr >> 2) & 7))) * 4 + (c & 3)];
    }
    *reinterpret_cast<float4*>(zqb + (size_t)c * 4096 + w4p * 4) =
        make_float4(ov[0], ov[1], ov[2], ov[3]);
  }
}

// ---- exact rescore: 8 rows/block, 2-deep pipelined cbT stream (small live
//      register set, no spill), single-barrier argmin. Same np numerics. ----
__global__ __launch_bounds__(256)
void vq_exact_fast(const float* __restrict__ zdump, const float* __restrict__ cbT,
                   const float* __restrict__ Bsg, const unsigned* __restrict__ list,
                   const unsigned* __restrict__ cnt, float* __restrict__ idxo) {
  __shared__ float zr[8][260];
  __shared__ float Anp[8];
  __shared__ float rvs[8][256];
  __shared__ int ris[8][256];
  const int t = threadIdx.x;
  const unsigned K = *cnt;
  const float4* cbT4 = reinterpret_cast<const float4*>(cbT);
  const float4* zd4 = reinterpret_cast<const float4*>(zdump);

  for (unsigned g = blockIdx.x; g * 8 < K; g += gridDim.x) {
    int nrows = (int)min(8u, K - g * 8);
    __syncthreads();                     // guard shared reuse across iterations
#pragma unroll
    for (int i = 0; i < 2; ++i) {
      int idx = t + i * 256;             // r = idx>>6, c4 = idx&63
      int r = idx >> 6, c4 = idx & 63;
      if (r < nrows) {
        float4 v = zd4[(size_t)list[g * 8 + r] * 64 + c4];
        zr[r][c4 * 4 + 0] = v.x; zr[r][c4 * 4 + 1] = v.y;
        zr[r][c4 * 4 + 2] = v.z; zr[r][c4 * 4 + 3] = v.w;
      }
    }
    __syncthreads();
    if (t < nrows) Anp[t] = np_sumsq256(&zr[t][0], 1);
    __syncthreads();

    // C chains: 2-deep pipelined cbT stream (c ascending per chain)
    float acc[8][4];
#pragma unroll
    for (int r = 0; r < 8; ++r)
#pragma unroll
      for (int q = 0; q < 4; ++q) acc[r][q] = 0.f;
    float4 pr0 = cbT4[0 * 256 + t];
    float4 pr1 = cbT4[1 * 256 + t];
    for (int c = 0; c < 256; c += 2) {
      float4 cur0 = pr0, cur1 = pr1;
      if (c + 2 < 256) {
        pr0 = cbT4[(c + 2) * 256 + t];
        pr1 = cbT4[(c + 3) * 256 + t];
      }
#pragma unroll
      for (int r = 0; r < 8; ++r) {
        float zc = zr[r][c];
        acc[r][0] = fmaf(zc, cur0.x, acc[r][0]);
        acc[r][1] = fmaf(zc, cur0.y, acc[r][1]);
        acc[r][2] = fmaf(zc, cur0.z, acc[r][2]);
        acc[r][3] = fmaf(zc, cur0.w, acc[r][3]);
      }
#pragma unroll
      for (int r = 0; r < 8; ++r) {
        float zc = zr[r][c + 1];
        acc[r][0] = fmaf(zc, cur1.x, acc[r][0]);
        acc[r][1] = fmaf(zc, cur1.y, acc[r][1]);
        acc[r][2] = fmaf(zc, cur1.z, acc[r][2]);
        acc[r][3] = fmaf(zc, cur1.w, acc[r][3]);
      }
    }

    // per-thread best over codes {4t..4t+3} per row -> LDS (first-index kept)
#pragma unroll
    for (int r = 0; r < 8; ++r) {
      float A = Anp[r];
      float bvv = 3.4e38f;
      int bii = 0;
#pragma unroll
      for (int q = 0; q < 4; ++q) {
        int j = t * 4 + q;
        float dd = __fsub_rn(__fadd_rn(A, Bsg[j]), __fmul_rn(2.0f, acc[r][q]));
        if (dd < bvv) { bvv = dd; bii = j; }
      }
      rvs[r][t] = bvv; ris[r][t] = bii;
    }
    __syncthreads();

    // single-barrier final reduce: 32 threads per row, strided scan + shfl
    {
      int r = t >> 5, s = t & 31;
      if (r < nrows) {
        float v0 = rvs[r][s]; int i0 = ris[r][s];
#pragma unroll
        for (int k = 1; k < 8; ++k) {
          float v = rvs[r][s + 32 * k]; int ii = ris[r][s + 32 * k];
          if (v < v0 || (v == v0 && ii < i0)) { v0 = v; i0 = ii; }
        }
#pragma unroll
        for (int mk = 1; mk < 32; mk <<= 1) {
          float v = __shfl_xor(v0, mk, 32); int ii = __shfl_xor(i0, mk, 32);
          if (v < v0 || (v == v0 && ii < i0)) { v0 = v; i0 = ii; }
        }
        if (s == 0) idxo[list[g * 8 + r]] = (float)i0;
      }
    }
  }
}

// ---- fallback (round-2 validated all-exact kernel) ----
__global__ __launch_bounds__(256)
void vq_ref(const float* __restrict__ z, const float* __restrict__ cb,
            float* __restrict__ zq, float* __restrict__ loss,
            float* __restrict__ idxo) {
  __shared__ __align__(16) float zt[256 * 64];
  __shared__ __align__(16) float cbt[256 * 64];
  __shared__ float As[64];
  __shared__ float Bs[64];
  __shared__ int bestj[64];
  __shared__ float cand_v[16 * 64];
  __shared__ int cand_i[16 * 64];
  __shared__ double wred[4];
  const int t = threadIdx.x;
  const int wg = t & 15, jg = t >> 4;
  const int bid = blockIdx.x;
  const int b = bid >> 6, h = bid & 63;
  const int n0 = bid * 64;
  const float4* z4 = reinterpret_cast<const float4*>(z + (size_t)b * 256 * 4096 + (size_t)h * 64);
  float4* zt4 = reinterpret_cast<float4*>(zt);
#pragma unroll
  for (int i = 0; i < 16; ++i) {
    int idx4 = t + i * 256;
    zt4[idx4] = z4[(size_t)(idx4 >> 4) * 1024 + (idx4 & 15)];
  }
  __syncthreads();
  if (t < 64) As[t] = np_sumsq256(zt + t, 64);
  float bv[4]; int bi[4];
#pragma unroll
  for (int a = 0; a < 4; ++a) { bv[a] = 3.4e38f; bi[a] = 0; }
  for (int p = 0; p < 16; ++p) {
    __syncthreads();
    const float4* cb4 = reinterpret_cast<const float4*>(cb) + (size_t)p * 64 * 64;
#pragma unroll
    for (int i = 0; i < 16; ++i) {
      int idx4 = t + i * 256;
      int jj = idx4 >> 6, c4 = idx4 & 63;
      float4 v = cb4[idx4];
      cbt[(c4 * 4 + 0) * 64 + jj] = v.x;
      cbt[(c4 * 4 + 1) * 64 + jj] = v.y;
      cbt[(c4 * 4 + 2) * 64 + jj] = v.z;
      cbt[(c4 * 4 + 3) * 64 + jj] = v.w;
    }
    __syncthreads();
    if (t < 64) Bs[t] = np_sumsq256(cbt + t, 64);
    float acc[4][4];
#pragma unroll
    for (int a = 0; a < 4; ++a)
#pragma unroll
      for (int u = 0; u < 4; ++u) acc[a][u] = 0.0f;
    const float4* ztp = reinterpret_cast<const float4*>(zt) + wg;
    const float4* cbp = reinterpret_cast<const float4*>(cbt) + jg;
#pragma unroll 4
    for (int c = 0; c < 256; ++c) {
      float4 zv = ztp[c * 16];
      float4 cv = cbp[c * 16];
      float za[4] = {zv.x, zv.y, zv.z, zv.w};
      float ca[4] = {cv.x, cv.y, cv.z, cv.w};
#pragma unroll
      for (int a = 0; a < 4; ++a)
#pragma unroll
        for (int u = 0; u < 4; ++u) acc[a][u] = fmaf(za[a], ca[u], acc[a][u]);
    }
    __syncthreads();
#pragma unroll
    for (int u = 0; u < 4; ++u) {
      int j = p * 64 + jg * 4 + u;
      float Bju = Bs[jg * 4 + u];
#pragma unroll
      for (int a = 0; a < 4; ++a) {
        float AB = __fadd_rn(As[wg * 4 + a], Bju);
        float dd = __fsub_rn(AB, __fmul_rn(2.0f, acc[a][u]));
        if (dd < bv[a]) { bv[a] = dd; bi[a] = j; }
      }
    }
  }
  __syncthreads();
#pragma unroll
  for (int a = 0; a < 4; ++a) {
    int w = wg * 4 + a;
    cand_v[jg * 64 + w] = bv[a];
    cand_i[jg * 64 + w] = bi[a];
  }
  __syncthreads();
  if (t < 64) {
    float v0 = cand_v[t]; int i0 = cand_i[t];
    for (int g = 1; g < 16; ++g) {
      float v = cand_v[g * 64 + t]; int ii = cand_i[g * 64 + t];
      if (v < v0 || (v == v0 && ii < i0)) { v0 = v; i0 = ii; }
    }
    bestj[t] = i0;
    idxo[n0 + t] = (float)i0;
  }
  __syncthreads();
  double lsum = 0.0;
  float* zqbase = zq + (size_t)b * 256 * 4096 + (size_t)h * 64;
  for (int i = 0; i < 64; ++i) {
    int idx = t + i * 256;
    int c = idx >> 6, w = idx & 63;
    float zvv = zt[c * 64 + w];
    float cvv = cb[(size_t)bestj[w] * 256 + c];
    zqbase[(size_t)c * 4096 + w] = cvv;
    double d = (double)cvv - (double)zvv;
    lsum += d * d;
  }
#pragma unroll
  for (int off = 32; off > 0; off >>= 1) lsum += __shfl_down(lsum, off, 64);
  if ((t & 63) == 0) wred[t >> 6] = lsum;
  __syncthreads();
  if (t == 0) {
    double tot = wred[0] + wred[1] + wred[2] + wred[3];
    atomicAdd(loss, (float)(tot * (1.25 / (double)NELEM)));
  }
}

extern "C" void kernel_launch(void* const* d_in, const int* in_sizes, int n_in,
                              void* d_out, int out_size, void* d_ws, size_t ws_size,
                              hipStream_t stream) {
  (void)in_sizes; (void)n_in; (void)out_size;
  const float* z = (const float*)d_in[0];
  const float* cb = (const float*)d_in[1];
  float* out = (float*)d_out;
  float* zq = out;
  float* loss = out + NELEM;
  float* idxo = out + NELEM + 1;
  if (ws_size < 35651584) {  // need zdump: else validated all-exact path
    hipMemsetAsync(loss, 0, sizeof(float), stream);
    vq_ref<<<512, 256, 0, stream>>>(z, cb, zq, loss, idxo);
    return;
  }
  unsigned char* ws = (unsigned char*)d_ws;
  unsigned* cnt = (unsigned*)ws;                             // 4 B
  float* Bsg = (float*)(ws + 1024);                          // 4 KB
  unsigned* list = (unsigned*)(ws + 8192);                   // 128 KB
  float* cbT = (float*)(ws + 139264);                        // 1 MB
  unsigned short* cbimg = (unsigned short*)(ws + 1187840);   // 512 KB fp16 frag-layout
  float* zdump = (float*)(ws + 2097152);                     // 32 MB (flagged rows only)
  vq_prep<<<64, 256, 0, stream>>>(cb, cbimg, cbT, Bsg, cnt, loss);
  vq_fast<<<1024, 256, 0, stream>>>(z, cb, cbimg, Bsg, zq, loss, idxo, list, cnt, zdump);
  vq_exact_fast<<<512, 256, 0, stream>>>(zdump, cbT, Bsg, list, cnt, idxo);
}

// Round 22
// 96.634 us; speedup vs baseline: 1.0884x; 1.0838x over previous
//
#include <hip/hip_runtime.h>
#include <hip/hip_fp16.h>

#define NELEM 8388608    // 8*256*64*64
#define M_GAP 6e-4f      // validated rounds 6/8/9/13 (fp16 1-plane, x1024 codebook)
#define SCORE_SCALE (-1.0f / 512.0f)

typedef _Float16 f16x8 __attribute__((ext_vector_type(8)));
typedef short s16x8 __attribute__((ext_vector_type(8)));
typedef float f32x4 __attribute__((ext_vector_type(4)));

__device__ __forceinline__ unsigned short bf16r(float f) {
  unsigned u = __float_as_uint(f);
  return (unsigned short)((u + 0x7fffu + ((u >> 16) & 1u)) >> 16);
}
__device__ __forceinline__ float bf16f(unsigned short h) {
  return __uint_as_float(((unsigned)h) << 16);
}

// numpy pairwise sum of squares (n=256): two 128-blocks of 8 accumulators.
__device__ __forceinline__ float pw128_sq(const float* p, int s) {
  float r[8];
#pragma unroll
  for (int j = 0; j < 8; ++j) { float v = p[j * s]; r[j] = __fmul_rn(v, v); }
#pragma unroll
  for (int i = 8; i < 128; i += 8) {
#pragma unroll
    for (int j = 0; j < 8; ++j) {
      float v = p[(i + j) * s];
      r[j] = __fadd_rn(r[j], __fmul_rn(v, v));
    }
  }
  return __fadd_rn(__fadd_rn(__fadd_rn(r[0], r[1]), __fadd_rn(r[2], r[3])),
                   __fadd_rn(__fadd_rn(r[4], r[5]), __fadd_rn(r[6], r[7])));
}
__device__ __forceinline__ float np_sumsq256(const float* p, int s) {
  return __fadd_rn(pw128_sq(p, s), pw128_sq(p + 128 * s, s));
}

// ---- prep (LDS transpose): 64 blocks, block b owns codes [b*16, b*16+16) ----
__global__ __launch_bounds__(256)
void vq_prep(const float* __restrict__ cb, unsigned short* __restrict__ cbimg,
             float* __restrict__ cbT, float* __restrict__ Bsg,
             unsigned* __restrict__ cnt, float* __restrict__ loss) {
  __shared__ float rows[16][260];
  const int t = threadIdx.x;
  const int b = blockIdx.x;            // tile T = b
  if (b == 0 && t == 0) { cnt[0] = 0u; *loss = 0.0f; }
#pragma unroll
  for (int i = 0; i < 4; ++i) {
    int idx = t + i * 256;             // r = idx>>6, c4 = idx&63
    int r = idx >> 6, c4 = idx & 63;
    float4 v = reinterpret_cast<const float4*>(cb + (size_t)(b * 16 + r) * 256)[c4];
    rows[r][c4 * 4 + 0] = v.x;
    rows[r][c4 * 4 + 1] = v.y;
    rows[r][c4 * 4 + 2] = v.z;
    rows[r][c4 * 4 + 3] = v.w;
  }
  __syncthreads();
  if (t < 16) Bsg[b * 16 + t] = np_sumsq256(&rows[t][0], 1);
  // cbimg frag layout: short idx T*4096 + kk*512 + (lk*16+jj)*8 + m
#pragma unroll
  for (int uu = 0; uu < 2; ++uu) {
    int u = t * 2 + uu;
    int kk = u >> 6, rem = u & 63;
    int lk = rem >> 4, jj = rem & 15;
    int c0 = kk * 32 + lk * 8;
    s16x8 hv;
#pragma unroll
    for (int m = 0; m < 8; ++m)
      hv[m] = (short)__half_as_ushort(__float2half(rows[jj][c0 + m] * 1024.0f));
    *reinterpret_cast<s16x8*>(cbimg + (size_t)b * 4096 + u * 8) = hv;
  }
  // cbT stripe: thread t = column c, 16 consecutive floats (line-efficient)
  {
    float* dst = cbT + (size_t)t * 1024 + b * 16;
#pragma unroll
    for (int jj = 0; jj < 16; ++jj) dst[jj] = rows[jj][t];
  }
}

// one 16-code tile: 8 kk MFMA x 2 row-subtiles + top-2 update; next tile's
// B-frag load issued right after ba[kk] is consumed. Macro so no register
// array is address-taken (rule #20).
#define VQ_STEP_PF(IT2, DO_PF)                                                 \
  {                                                                            \
    f32x4 acc[2];                                                              \
    acc[0] = (f32x4){0.f, 0.f, 0.f, 0.f};                                      \
    acc[1] = (f32x4){0.f, 0.f, 0.f, 0.f};                                      \
    _Pragma("unroll")                                                          \
    for (int kk = 0; kk < 8; ++kk) {                                           \
      f16x8 bcur = ba[kk];                                                     \
      if (DO_PF)                                                               \
        ba[kk] = cimg2[(size_t)(wv * 16 + (IT2) + 1) * 512 + kk * 64 + lane];  \
      _Pragma("unroll")                                                        \
      for (int rs = 0; rs < 2; ++rs)                                           \
        acc[rs] = __builtin_amdgcn_mfma_f32_16x16x32_f16(ah[rs][kk], bcur,     \
                                                         acc[rs], 0, 0, 0);    \
    }                                                                          \
    int j = wv * 256 + (IT2) * 16 + l15;                                       \
    float Bj = BsL[j];                                                         \
    _Pragma("unroll")                                                          \
    for (int rs = 0; rs < 2; ++rs) {                                           \
      _Pragma("unroll")                                                        \
      for (int r = 0; r < 4; ++r) {                                            \
        float s = fmaf(SCORE_SCALE, acc[rs][r], Bj);                           \
        bool lt = s < b1v[rs][r];                                              \
        float other = lt ? b1v[rs][r] : s;                                     \
        b2v[rs][r] = fminf(b2v[rs][r], other);                                 \
        b1v[rs][r] = fminf(b1v[rs][r], s);                                     \
        b1i[rs][r] = lt ? j : b1i[rs][r];                                      \
      }                                                                        \
    }                                                                          \
  }

// ---- fast: 1024 blocks x 32 rows, 4 waves code-partitioned, B global->reg ----
__global__ __launch_bounds__(256, 1)
void vq_fast(const float* __restrict__ z, const float* __restrict__ cb,
             const unsigned short* __restrict__ cbimg,
             const float* __restrict__ Bsg,
             float* __restrict__ zq, float* __restrict__ loss,
             float* __restrict__ idxo,
             unsigned* __restrict__ list, unsigned* __restrict__ cnt,
             float* __restrict__ zdump) {
  __shared__ __align__(16) unsigned char buf[33792]; // zt[256][33] f32 / epilogue ldsF 32KB
  __shared__ float BsL[1024];
  __shared__ float part[32][33];
  __shared__ float rowA[32];
  __shared__ int bestj[32];
  __shared__ float bestd[32];
  __shared__ unsigned char flg[32];
  __shared__ float wred[4];
  __shared__ float cv1[4 * 32], cv2[4 * 32];
  __shared__ int ci1[4 * 32];

  const int t = threadIdx.x;
  const int bid = blockIdx.x;          // rows n0 = bid*32
  const int lane = t & 63;
  const int wv = t >> 6;               // wave 0..3: codes wv*256..+255
  const int l15 = lane & 15;
  const int lk = lane >> 4;            // 0..3
  const int bh = bid >> 1, half = bid & 1;

  const f16x8* cimg2 = reinterpret_cast<const f16x8*>(cbimg);  // 16B units
  float* zt = reinterpret_cast<float*>(buf);   // [256 c][33] f32 during A-stage
  const float4* z4 = reinterpret_cast<const float4*>(
      z + (size_t)(bh >> 6) * 1048576 + (size_t)(bh & 63) * 64 + half * 32);

  // issue tile-0 loads of this wave's quarter early (latency under A-stage)
  f16x8 ba[8];
#pragma unroll
  for (int kk = 0; kk < 8; ++kk)
    ba[kk] = cimg2[(size_t)(wv * 16) * 512 + kk * 64 + lane];

  for (int i = t; i < 1024; i += 256) BsL[i] = Bsg[i];

  // ---- A staging: 32 rows in one pass ----
  {
    float sq[4] = {0.f, 0.f, 0.f, 0.f};
#pragma unroll
    for (int i = 0; i < 8; ++i) {
      int idx = t + i * 256;           // c = idx>>3, w4p = idx&7
      int c = idx >> 3, w4p = idx & 7;
      float4 v = z4[(size_t)c * 1024 + w4p];
      zt[c * 33 + w4p * 4 + 0] = v.x;
      zt[c * 33 + w4p * 4 + 1] = v.y;
      zt[c * 33 + w4p * 4 + 2] = v.z;
      zt[c * 33 + w4p * 4 + 3] = v.w;
      sq[0] += v.x * v.x; sq[1] += v.y * v.y;
      sq[2] += v.z * v.z; sq[3] += v.w * v.w;
    }
#pragma unroll
    for (int q = 0; q < 4; ++q) part[t >> 3][(t & 7) * 4 + q] = sq[q];
  }
  __syncthreads();
  if (t < 32) {
    float s = 0.f;
#pragma unroll
    for (int g = 0; g < 32; ++g) s += part[g][t];
    rowA[t] = s;
  }

  // a-frags: all 32 rows (2 subtiles), fp16 RNE
  f16x8 ah[2][8];
#pragma unroll
  for (int rs = 0; rs < 2; ++rs)
#pragma unroll
    for (int kk = 0; kk < 8; ++kk)
#pragma unroll
      for (int m = 0; m < 8; ++m)
        ah[rs][kk][m] = (_Float16)zt[(kk * 32 + lk * 8 + m) * 33 + rs * 16 + l15];
  __syncthreads();

  float b1v[2][4], b2v[2][4];
  int b1i[2][4];
#pragma unroll
  for (int rs = 0; rs < 2; ++rs)
#pragma unroll
    for (int r = 0; r < 4; ++r) { b1v[rs][r] = 3.4e38f; b2v[rs][r] = 3.4e38f; b1i[rs][r] = 0; }

  // barrier-free main loop over this wave's 16 private tiles
  for (int it = 0; it < 15; ++it) {
    VQ_STEP_PF(it, true);
  }
  VQ_STEP_PF(15, false);

  // ---- merge top-2 across the 16 lanes sharing rows (within wave) ----
#pragma unroll
  for (int mk = 1; mk < 16; mk <<= 1) {
#pragma unroll
    for (int rs = 0; rs < 2; ++rs)
#pragma unroll
      for (int r = 0; r < 4; ++r) {
        float ov1 = __shfl_xor(b1v[rs][r], mk, 64);
        float ov2 = __shfl_xor(b2v[rs][r], mk, 64);
        int oi1 = __shfl_xor(b1i[rs][r], mk, 64);
        bool lt = ov1 < b1v[rs][r];
        float hi = lt ? b1v[rs][r] : ov1;
        b2v[rs][r] = fminf(fminf(b2v[rs][r], ov2), hi);
        b1v[rs][r] = fminf(b1v[rs][r], ov1);
        b1i[rs][r] = lt ? oi1 : b1i[rs][r];
      }
  }
  if (l15 == 0) {
#pragma unroll
    for (int rs = 0; rs < 2; ++rs)
#pragma unroll
      for (int r = 0; r < 4; ++r) {
        int rr = rs * 16 + lk * 4 + r;     // D row = (lane>>4)*4 + reg
        cv1[wv * 32 + rr] = b1v[rs][r];
        cv2[wv * 32 + rr] = b2v[rs][r];
        ci1[wv * 32 + rr] = b1i[rs][r];
      }
  }
  __syncthreads();

  // ---- cross-wave merge (wave order = ascending code ranges) ----
  if (t < 32) {
    float v1 = cv1[t], v2 = cv2[t];
    int i1 = ci1[t];
#pragma unroll
    for (int w = 1; w < 4; ++w) {
      float u1 = cv1[w * 32 + t], u2 = cv2[w * 32 + t];
      int ui = ci1[w * 32 + t];
      if (u1 < v1) { v2 = fminf(v1, u2); v1 = u1; i1 = ui; }
      else v2 = fminf(v2, u1);
    }
    bestj[t] = i1;
    bestd[t] = v1;
    flg[t] = (v2 - v1 <= M_GAP) ? 1 : 0;
    int n = bid * 32 + t;
    idxo[n] = (float)i1;               // provisional for flagged rows
    if (flg[t]) { unsigned pos = atomicAdd(cnt, 1u); list[pos] = (unsigned)n; }
  }
  __syncthreads();

  // ---- zdump ONLY for flagged rows (zt still live in buf) ----
  for (int rr = 0; rr < 32; ++rr) {
    if (flg[rr])
      zdump[((size_t)bid * 32 + rr) * 256 + t] = zt[t * 33 + rr];
  }

  // loss over ALL rows (flagged rows' provisional s_best within tolerance)
  {
    float lv = (t < 32) ? (rowA[t] + bestd[t]) : 0.f;
#pragma unroll
    for (int off = 32; off > 0; off >>= 1) lv += __shfl_down(lv, off, 64);
    if (lane == 0) wred[wv] = lv;
  }
  __syncthreads();
  if (t == 0)
    atomicAdd(loss, (wred[0] + wred[1] + wred[2] + wred[3]) * (1.25f / (float)NELEM));
  __syncthreads();   // zdump reads of zt done before buf is reused below

  // ---- zq gather: cb rows -> LDS transpose -> coalesced write (32 rows) ----
  f32x4* ldsF4 = reinterpret_cast<f32x4*>(buf);
  const float* ldsF = reinterpret_cast<const float*>(buf);
  const float4* cb4 = reinterpret_cast<const float4*>(cb);
  float* zqb = zq + (size_t)(bh >> 6) * 1048576 + (size_t)(bh & 63) * 64 + half * 32;
#pragma unroll
  for (int i = 0; i < 8; ++i) {
    int item = t + i * 256;            // rr = item>>6 in [0,32), cc = item&63
    int rr = item >> 6, cc = item & 63;
    float4 v = cb4[(size_t)bestj[rr] * 64 + cc];
    ldsF4[rr * 64 + (cc ^ ((rr >> 2) & 7))] = (f32x4){v.x, v.y, v.z, v.w};
  }
  __syncthreads();
#pragma unroll
  for (int i = 0; i < 8; ++i) {
    int item = t + i * 256;            // w4p = item&7, c = item>>3
    int w4p = item & 7, c = item >> 3;
    float ov[4];
#pragma unroll
    for (int q = 0; q < 4; ++q) {
      int rr = w4p * 4 + q;
      ov[q] = ldsF[(rr * 64 + ((c >> 2) ^ ((rr >> 2) & 7))) * 4 + (c & 3)];
    }
    *reinterpret_cast<float4*>(zqb + (size_t)c * 4096 + w4p * 4) =
        make_float4(ov[0], ov[1], ov[2], ov[3]);
  }
}

// ---- exact rescore: batched 8 rows, coalesced zdump + cbT, idx-only ----
__global__ __launch_bounds__(256)
void vq_exact_fast(const float* __restrict__ zdump, const float* __restrict__ cbT,
                   const float* __restrict__ Bsg, const unsigned* __restrict__ list,
                   const unsigned* __restrict__ cnt, float* __restrict__ idxo) {
  __shared__ float zr[8][260];
  __shared__ float Anp[8];
  __shared__ float rv[256];
  __shared__ int ri[256];
  const int t = threadIdx.x;
  const unsigned K = *cnt;
  const float4* cbT4 = reinterpret_cast<const float4*>(cbT);
  const float4* zd4 = reinterpret_cast<const float4*>(zdump);

  for (unsigned g = blockIdx.x; g * 8 < K; g += gridDim.x) {
    int nrows = (int)min(8u, K - g * 8);
    __syncthreads();
#pragma unroll
    for (int i = 0; i < 2; ++i) {
      int idx = t + i * 256;             // r = idx>>6, c4 = idx&63
      int r = idx >> 6, c4 = idx & 63;
      if (r < nrows) {
        float4 v = zd4[(size_t)list[g * 8 + r] * 64 + c4];
        zr[r][c4 * 4 + 0] = v.x; zr[r][c4 * 4 + 1] = v.y;
        zr[r][c4 * 4 + 2] = v.z; zr[r][c4 * 4 + 3] = v.w;
      }
    }
    __syncthreads();
    if (t < nrows) Anp[t] = np_sumsq256(&zr[t][0], 1);
    __syncthreads();

    float acc[8][4];
#pragma unroll
    for (int r = 0; r < 8; ++r)
#pragma unroll
      for (int q = 0; q < 4; ++q) acc[r][q] = 0.f;
    for (int c = 0; c < 256; ++c) {
      float4 bv = cbT4[c * 256 + t];
#pragma unroll
      for (int r = 0; r < 8; ++r) {
        float zc = zr[r][c];
        acc[r][0] = fmaf(zc, bv.x, acc[r][0]);
        acc[r][1] = fmaf(zc, bv.y, acc[r][1]);
        acc[r][2] = fmaf(zc, bv.z, acc[r][2]);
        acc[r][3] = fmaf(zc, bv.w, acc[r][3]);
      }
    }
    for (int r = 0; r < nrows; ++r) {
      float A = Anp[r];
      float bvv = 3.4e38f;
      int bii = 0;
#pragma unroll
      for (int q = 0; q < 4; ++q) {
        int j = t * 4 + q;
        float dd = __fsub_rn(__fadd_rn(A, Bsg[j]), __fmul_rn(2.0f, acc[r][q]));
        if (dd < bvv) { bvv = dd; bii = j; }
      }
      rv[t] = bvv; ri[t] = bii;
      __syncthreads();
      for (int s2 = 128; s2 > 0; s2 >>= 1) {
        if (t < s2) {
          float v2 = rv[t + s2]; int i2 = ri[t + s2];
          if (v2 < rv[t] || (v2 == rv[t] && i2 < ri[t])) { rv[t] = v2; ri[t] = i2; }
        }
        __syncthreads();
      }
      if (t == 0) idxo[list[g * 8 + r]] = (float)ri[0];
      __syncthreads();
    }
  }
}

// ---- fallback (round-2 validated all-exact kernel) ----
__global__ __launch_bounds__(256)
void vq_ref(const float* __restrict__ z, const float* __restrict__ cb,
            float* __restrict__ zq, float* __restrict__ loss,
            float* __restrict__ idxo) {
  __shared__ __align__(16) float zt[256 * 64];
  __shared__ __align__(16) float cbt[256 * 64];
  __shared__ float As[64];
  __shared__ float Bs[64];
  __shared__ int bestj[64];
  __shared__ float cand_v[16 * 64];
  __shared__ int cand_i[16 * 64];
  __shared__ double wred[4];
  const int t = threadIdx.x;
  const int wg = t & 15, jg = t >> 4;
  const int bid = blockIdx.x;
  const int b = bid >> 6, h = bid & 63;
  const int n0 = bid * 64;
  const float4* z4 = reinterpret_cast<const float4*>(z + (size_t)b * 256 * 4096 + (size_t)h * 64);
  float4* zt4 = reinterpret_cast<float4*>(zt);
#pragma unroll
  for (int i = 0; i < 16; ++i) {
    int idx4 = t + i * 256;
    zt4[idx4] = z4[(size_t)(idx4 >> 4) * 1024 + (idx4 & 15)];
  }
  __syncthreads();
  if (t < 64) As[t] = np_sumsq256(zt + t, 64);
  float bv[4]; int bi[4];
#pragma unroll
  for (int a = 0; a < 4; ++a) { bv[a] = 3.4e38f; bi[a] = 0; }
  for (int p = 0; p < 16; ++p) {
    __syncthreads();
    const float4* cb4 = reinterpret_cast<const float4*>(cb) + (size_t)p * 64 * 64;
#pragma unroll
    for (int i = 0; i < 16; ++i) {
      int idx4 = t + i * 256;
      int jj = idx4 >> 6, c4 = idx4 & 63;
      float4 v = cb4[idx4];
      cbt[(c4 * 4 + 0) * 64 + jj] = v.x;
      cbt[(c4 * 4 + 1) * 64 + jj] = v.y;
      cbt[(c4 * 4 + 2) * 64 + jj] = v.z;
      cbt[(c4 * 4 + 3) * 64 + jj] = v.w;
    }
    __syncthreads();
    if (t < 64) Bs[t] = np_sumsq256(cbt + t, 64);
    float acc[4][4];
#pragma unroll
    for (int a = 0; a < 4; ++a)
#pragma unroll
      for (int u = 0; u < 4; ++u) acc[a][u] = 0.0f;
    const float4* ztp = reinterpret_cast<const float4*>(zt) + wg;
    const float4* cbp = reinterpret_cast<const float4*>(cbt) + jg;
#pragma unroll 4
    for (int c = 0; c < 256; ++c) {
      float4 zv = ztp[c * 16];
      float4 cv = cbp[c * 16];
      float za[4] = {zv.x, zv.y, zv.z, zv.w};
      float ca[4] = {cv.x, cv.y, cv.z, cv.w};
#pragma unroll
      for (int a = 0; a < 4; ++a)
#pragma unroll
        for (int u = 0; u < 4; ++u) acc[a][u] = fmaf(za[a], ca[u], acc[a][u]);
    }
    __syncthreads();
#pragma unroll
    for (int u = 0; u < 4; ++u) {
      int j = p * 64 + jg * 4 + u;
      float Bju = Bs[jg * 4 + u];
#pragma unroll
      for (int a = 0; a < 4; ++a) {
        float AB = __fadd_rn(As[wg * 4 + a], Bju);
        float dd = __fsub_rn(AB, __fmul_rn(2.0f, acc[a][u]));
        if (dd < bv[a]) { bv[a] = dd; bi[a] = j; }
      }
    }
  }
  __syncthreads();
#pragma unroll
  for (int a = 0; a < 4; ++a) {
    int w = wg * 4 + a;
    cand_v[jg * 64 + w] = bv[a];
    cand_i[jg * 64 + w] = bi[a];
  }
  __syncthreads();
  if (t < 64) {
    float v0 = cand_v[t]; int i0 = cand_i[t];
    for (int g = 1; g < 16; ++g) {
      float v = cand_v[g * 64 + t]; int ii = cand_i[g * 64 + t];
      if (v < v0 || (v == v0 && ii < i0)) { v0 = v; i0 = ii; }
    }
    bestj[t] = i0;
    idxo[n0 + t] = (float)i0;
  }
  __syncthreads();
  double lsum = 0.0;
  float* zqbase = zq + (size_t)b * 256 * 4096 + (size_t)h * 64;
  for (int i = 0; i < 64; ++i) {
    int idx = t + i * 256;
    int c = idx >> 6, w = idx & 63;
    float zvv = zt[c * 64 + w];
    float cvv = cb[(size_t)bestj[w] * 256 + c];
    zqbase[(size_t)c * 4096 + w] = cvv;
    double d = (double)cvv - (double)zvv;
    lsum += d * d;
  }
#pragma unroll
  for (int off = 32; off > 0; off >>= 1) lsum += __shfl_down(lsum, off, 64);
  if ((t & 63) == 0) wred[t >> 6] = lsum;
  __syncthreads();
  if (t == 0) {
    double tot = wred[0] + wred[1] + wred[2] + wred[3];
    atomicAdd(loss, (float)(tot * (1.25 / (double)NELEM)));
  }
}

extern "C" void kernel_launch(void* const* d_in, const int* in_sizes, int n_in,
                              void* d_out, int out_size, void* d_ws, size_t ws_size,
                              hipStream_t stream) {
  (void)in_sizes; (void)n_in; (void)out_size;
  const float* z = (const float*)d_in[0];
  const float* cb = (const float*)d_in[1];
  float* out = (float*)d_out;
  float* zq = out;
  float* loss = out + NELEM;
  float* idxo = out + NELEM + 1;
  if (ws_size < 35651584) {  // need zdump: else validated all-exact path
    hipMemsetAsync(loss, 0, sizeof(float), stream);
    vq_ref<<<512, 256, 0, stream>>>(z, cb, zq, loss, idxo);
    return;
  }
  unsigned char* ws = (unsigned char*)d_ws;
  unsigned* cnt = (unsigned*)ws;                             // 4 B
  float* Bsg = (float*)(ws + 1024);                          // 4 KB
  unsigned* list = (unsigned*)(ws + 8192);                   // 128 KB
  float* cbT = (float*)(ws + 139264);                        // 1 MB
  unsigned short* cbimg = (unsigned short*)(ws + 1187840);   // 512 KB fp16 frag-layout
  float* zdump = (float*)(ws + 2097152);                     // 32 MB (flagged rows only)
  vq_prep<<<64, 256, 0, stream>>>(cb, cbimg, cbT, Bsg, cnt, loss);
  vq_fast<<<1024, 256, 0, stream>>>(z, cb, cbimg, Bsg, zq, loss, idxo, list, cnt, zdump);
  vq_exact_fast<<<512, 256, 0, stream>>>(zdump, cbT, Bsg, list, cnt, idxo);
}